// Round 13
// baseline (396.659 us; speedup 1.0000x reference)
//
#include <hip/hip_runtime.h>

typedef unsigned short u16;
typedef __attribute__((ext_vector_type(8))) short bf16x8;   // 8 bf16 in 4 VGPRs
typedef __attribute__((ext_vector_type(4))) float f32x4;

__device__ __forceinline__ float bf2f(unsigned int u) {
    union { unsigned int i; float f; } c; c.i = u << 16; return c.f;
}
__device__ __forceinline__ unsigned int f2bf(float f) {
    union { float f; unsigned int i; } c; c.f = f;
    unsigned int x = c.i;
    unsigned int r = x + 0x7FFFu + ((x >> 16) & 1u);
    return r >> 16;  // RNE; finite inputs
}

// async 16B global->LDS DMA. LDS dest = wave-uniform base + lane*16 (linear!).
__device__ __forceinline__ void gload_lds16(const u16* g, u16* l) {
    __builtin_amdgcn_global_load_lds(
        (__attribute__((address_space(1))) void*)const_cast<u16*>(g),
        (__attribute__((address_space(3))) void*)l,
        16, 0, 0);
}

// ---- weight convert+transpose: W fp32 [K][N] -> Wt bf16 [N][K], 32x32 LDS tiles ----
__global__ __launch_bounds__(256) void wconv_kernel(const float* __restrict__ W,
                                                    u16* __restrict__ Wt, int K, int N) {
    __shared__ u16 tile[32][36];
    int k0 = blockIdx.y * 32, n0 = blockIdx.x * 32;
    int t = threadIdx.x;
    int r = t >> 3, c4 = (t & 7) * 4;
    float4 v = *(const float4*)(W + (size_t)(k0 + r) * N + n0 + c4);
    tile[r][c4 + 0] = (u16)f2bf(v.x);
    tile[r][c4 + 1] = (u16)f2bf(v.y);
    tile[r][c4 + 2] = (u16)f2bf(v.z);
    tile[r][c4 + 3] = (u16)f2bf(v.w);
    __syncthreads();
    int n = t >> 3, k4 = (t & 7) * 4;
    u16 a0 = tile[k4 + 0][n], a1 = tile[k4 + 1][n];
    u16 a2 = tile[k4 + 2][n], a3 = tile[k4 + 3][n];
    uint2 st;
    st.x = (unsigned)a0 | ((unsigned)a1 << 16);
    st.y = (unsigned)a2 | ((unsigned)a3 << 16);
    *(uint2*)(Wt + (size_t)(n0 + n) * K + k0 + k4) = st;
}

// ---- LayerNorm fp32 in -> bf16 out. 256 threads = 4 waves, one row (512) per wave ----
__global__ __launch_bounds__(256) void ln_kernel(const float* __restrict__ x,
                                                 const float* __restrict__ g,
                                                 const float* __restrict__ b,
                                                 u16* __restrict__ y) {
    int row = blockIdx.x * 4 + (threadIdx.x >> 6);
    int t = threadIdx.x & 63;
    const float* xr = x + (size_t)row * 512 + t * 8;
    float4 a = *(const float4*)xr;
    float4 c = *(const float4*)(xr + 4);
    float v[8] = { a.x, a.y, a.z, a.w, c.x, c.y, c.z, c.w };
    float s = 0.f, ss = 0.f;
#pragma unroll
    for (int i = 0; i < 8; ++i) { s += v[i]; ss += v[i] * v[i]; }
#pragma unroll
    for (int off = 32; off; off >>= 1) {
        s  += __shfl_down(s, off);
        ss += __shfl_down(ss, off);
    }
    s = __shfl(s, 0); ss = __shfl(ss, 0);
    float mu = s * (1.0f / 512.0f);
    float var = ss * (1.0f / 512.0f) - mu * mu;
    float r = rsqrtf(var + 1e-5f);
    float4 g0 = *(const float4*)(g + t * 8);
    float4 g1 = *(const float4*)(g + t * 8 + 4);
    float4 b0 = *(const float4*)(b + t * 8);
    float4 b1 = *(const float4*)(b + t * 8 + 4);
    float gv[8] = { g0.x, g0.y, g0.z, g0.w, g1.x, g1.y, g1.z, g1.w };
    float bv[8] = { b0.x, b0.y, b0.z, b0.w, b1.x, b1.y, b1.z, b1.w };
    unsigned int o[4];
#pragma unroll
    for (int i = 0; i < 4; ++i) {
        float o0 = (v[2 * i] - mu) * r * gv[2 * i] + bv[2 * i];
        float o1 = (v[2 * i + 1] - mu) * r * gv[2 * i + 1] + bv[2 * i + 1];
        o[i] = f2bf(o0) | (f2bf(o1) << 16);
    }
    *(uint4*)(y + (size_t)row * 512 + t * 8) = make_uint4(o[0], o[1], o[2], o[3]);
}

// ---- MFMA GEMM: C[M,N] = act(A[M,K]bf16 @ Bt[N,K]bf16^T + bias fp32) (+res fp32) ----
// 64xBN tile (BN in {64,128}), K-step 64 as TWO 32-planes, 2-phase double-buffered
// (measured-best structure: STAGE(next) before compute, one __syncthreads per 64-K).
// BN=64 for the N=512 GEMMs (2 blocks/CU); BN=128 for qkv/fc1.
// 1D grid + XCD chunk-swizzle: wg = (bid&7)*(G/8) + bid>>3 (G%8==0).
template <int ACT, int RES, int COUT, int BN>
__global__ __launch_bounds__(256) void gemm_mfma(const u16* __restrict__ A, int lda,
                                                 const u16* __restrict__ Bt,
                                                 const float* __restrict__ bias,
                                                 const float* __restrict__ res, int ldres,
                                                 void* __restrict__ C, int ldC, int K,
                                                 int gx) {
    constexpr int JN = BN / 32;          // N-frags per wave (128->4, 64->2)
    __shared__ u16 As[2][2][64 * 32];    // [buf][plane][row][32] linear (gload_lds dest)
    __shared__ u16 Bs[2][2][BN * 32];
    int tid = threadIdx.x;
    int G = gridDim.x;
    int bid = blockIdx.x;
    int wg = (bid & 7) * (G >> 3) + (bid >> 3);   // XCD-contiguous chunks
    int bm = (wg / gx) * 64, bn = (wg % gx) * BN;
    int lane = tid & 63, wv = tid >> 6;
    int q = lane >> 4, lr = lane & 15;
    int wr = wv >> 1, wc = wv & 1;

    // staging (per 32-plane): A: wave wv rows [wv*16,+16), 1 instr (lane: row l>>2,
    // col (l&3)*8). B: wave wv rows [wv*(BN/4),+BN/4): 2 instrs if BN=128, 1 if 64.
    const u16* Ag = A + (size_t)(bm + wv * 16 + (lane >> 2)) * lda + (lane & 3) * 8;
    const u16* Bg = Bt + (size_t)(bn + wv * (BN / 4) + (lane >> 2)) * K + (lane & 3) * 8;
    int aoff  = (wv * 16) * 32;
    int boff0 = (wv * (BN / 4)) * 32;
    int boff1 = (wv * (BN / 4) + 16) * 32;   // BN==128 only
    int apf = (wr * 32 + lr) * 32 + q * 8;
    int bpf = (wc * (BN / 2) + lr) * 32 + q * 8;

    f32x4 acc[2][JN];
#pragma unroll
    for (int i = 0; i < 2; ++i)
#pragma unroll
        for (int j = 0; j < JN; ++j) acc[i][j] = (f32x4){0.f, 0.f, 0.f, 0.f};

    // prologue: stage k-tile 0 (both planes) into buf 0
#pragma unroll
    for (int p = 0; p < 2; ++p) {
        gload_lds16(Ag + p * 32, &As[0][p][aoff]);
        gload_lds16(Bg + p * 32, &Bs[0][p][boff0]);
        if constexpr (BN == 128)
            gload_lds16(Bg + (size_t)16 * K + p * 32, &Bs[0][p][boff1]);
    }
    __syncthreads();   // vmcnt(0) drain: tile 0 in LDS

    int cur = 0;
    for (int k0 = 0; k0 < K; k0 += 64) {
        int nxt = cur ^ 1;
        if (k0 + 64 < K) {   // issue next 64-K tile; overlaps both compute planes below
#pragma unroll
            for (int p = 0; p < 2; ++p) {
                gload_lds16(Ag + k0 + 64 + p * 32, &As[nxt][p][aoff]);
                gload_lds16(Bg + k0 + 64 + p * 32, &Bs[nxt][p][boff0]);
                if constexpr (BN == 128)
                    gload_lds16(Bg + (size_t)16 * K + k0 + 64 + p * 32, &Bs[nxt][p][boff1]);
            }
        }
#pragma unroll
        for (int p = 0; p < 2; ++p) {
            bf16x8 af[2], bfr[JN];
#pragma unroll
            for (int i = 0; i < 2; ++i) af[i] = *(const bf16x8*)&As[cur][p][apf + i * 16 * 32];
#pragma unroll
            for (int j = 0; j < JN; ++j) bfr[j] = *(const bf16x8*)&Bs[cur][p][bpf + j * 16 * 32];
#pragma unroll
            for (int i = 0; i < 2; ++i)
#pragma unroll
                for (int j = 0; j < JN; ++j)
                    acc[i][j] = __builtin_amdgcn_mfma_f32_16x16x32_bf16(af[i], bfr[j], acc[i][j], 0, 0, 0);
        }
        __syncthreads();   // drains prefetch vmcnt + all waves done with buf[cur]
        cur = nxt;
    }

    float bv[JN];
#pragma unroll
    for (int j = 0; j < JN; ++j)
        bv[j] = bias ? bias[bn + wc * (BN / 2) + j * 16 + lr] : 0.f;
#pragma unroll
    for (int i = 0; i < 2; ++i) {
#pragma unroll
        for (int j = 0; j < JN; ++j) {
            int col = bn + wc * (BN / 2) + j * 16 + lr;
#pragma unroll
            for (int r = 0; r < 4; ++r) {
                int row = bm + wr * 32 + i * 16 + q * 4 + r;
                float v = acc[i][j][r] + bv[j];
                if (ACT) v = 0.5f * v * (1.0f + erff(v * 0.7071067811865475f));
                if (RES) v += res[(size_t)row * ldres + col];
                if (COUT == 0) ((u16*)C)[(size_t)row * ldC + col] = (u16)f2bf(v);
                else           ((float*)C)[(size_t)row * ldC + col] = v;
            }
        }
    }
}

// ---- Flash attention (MFMA): 1D grid 1024, XCD-grouped decode (K/V + bias column
// fetched once per XCD). qkv: [4096][1536] bf16; Q [0,512), K [512,1024), V [1024,1536).
// biasc: per-block window [qt*126, qt*126+2112), stored BF16 -> block LDS 40576 B
// (<= 40960) -> 4 blocks/CU (was 3 at fp32). Latency-bound kernel: +33% resident
// waves is the lever; bf2f lookup adds 1 shift/bias (~1% VALU).
// Core: fp32 math, __expf + shfl-sum softmax, row-contiguous K/V staging w/ prefetch.
__global__ __launch_bounds__(256) void attn_mfma(u16* __restrict__ qkv,
                                                 const float* __restrict__ bias_table) {
    __shared__ u16 Ks[128][40];        // [key][d]  stride 80B (16B-aligned)
    __shared__ u16 Vt[32][136];        // [d][key]  stride 272B
    __shared__ u16 Ps[4][16][136];     // per-wave P stage [row][key]
    __shared__ u16 biasc[2112];        // bias window, bf16
    int tid = threadIdx.x;
    int bid = blockIdx.x;
    // decode: xcd = bid&7, i = bid>>3; group = xcd*8 + (i>>4) in [0,64); qt = i&15
    int grp = (bid & 7) * 8 + ((bid >> 3) >> 4);
    int qt = (bid >> 3) & 15;
    int h = grp & 15, z = grp >> 4;
    u16* qkvz = qkv + (size_t)z * 1024 * 1536;

    int bbase = qt * 126;
    for (int i = tid; i < 2112; i += 256) {
        int gi = bbase + i;
        if (gi < 3969) biasc[i] = (u16)f2bf(bias_table[(size_t)gi * 16 + h]);
    }

    int lane = tid & 63, wv = tid >> 6;
    int q = lane >> 4, m = lane & 15;

    // Q A-fragment (held for the whole block): rows qt*64 + wv*16 + m
    int qrow = qt * 64 + wv * 16 + m;
    bf16x8 qf = *(const bf16x8*)(qkvz + (size_t)qrow * 1536 + h * 32 + q * 8);

    // local bias base: idx_local = arow[r] - bb, arow = (inner>>5)*63 + (inner&31) + 1984
    int arow[4];
#pragma unroll
    for (int r = 0; r < 4; ++r) {
        int inner = wv * 16 + q * 4 + r;
        arow[r] = (inner >> 5) * 63 + (inner & 31) + 1984;
    }

    const float scale = 0.17677669529663687f;  // 1/sqrt(32)
    float mrow[4] = { -1e30f, -1e30f, -1e30f, -1e30f };
    float lrow[4] = { 0.f, 0.f, 0.f, 0.f };
    f32x4 acco[2] = { (f32x4){0.f,0.f,0.f,0.f}, (f32x4){0.f,0.f,0.f,0.f} };

    // K/V staging assignment + software-pipelined prefetch (issue-early / write-late)
    int key = tid >> 1, dh = (tid & 1) * 16;
    const u16* kvsrc = qkvz + (size_t)key * 1536 + 512 + h * 32 + dh;  // K of key row
    uint4 pk0, pk1, pv0, pv1;
    pk0 = *(const uint4*)(kvsrc);
    pk1 = *(const uint4*)(kvsrc + 8);
    pv0 = *(const uint4*)(kvsrc + 512);     // V is +512 cols from K
    pv1 = *(const uint4*)(kvsrc + 520);

    for (int kt = 0; kt < 8; ++kt) {
        __syncthreads();   // all waves done reading Ks/Vt of tile kt-1 (covers biasc at kt=0)
        *(uint4*)&Ks[key][dh] = pk0;
        *(uint4*)&Ks[key][dh + 8] = pk1;
        {
            u16 tmp[16];
            *(uint4*)tmp = pv0; *(uint4*)(tmp + 8) = pv1;
#pragma unroll
            for (int j = 0; j < 16; ++j) Vt[dh + j][key] = tmp[j];
        }
        __syncthreads();
        if (kt < 7) {   // issue next tile's loads now; latency hides under compute below
            const u16* src = kvsrc + (size_t)(kt + 1) * 128 * 1536;
            pk0 = *(const uint4*)(src);
            pk1 = *(const uint4*)(src + 8);
            pv0 = *(const uint4*)(src + 512);
            pv1 = *(const uint4*)(src + 520);
        }

        // QK: 8 sub-tiles of 16 keys, full hd=32 in one MFMA each
        f32x4 s8[8];
#pragma unroll
        for (int t = 0; t < 8; ++t) {
            bf16x8 kf = *(const bf16x8*)&Ks[t * 16 + m][q * 8];
            s8[t] = __builtin_amdgcn_mfma_f32_16x16x32_bf16(
                qf, kf, (f32x4){0.f,0.f,0.f,0.f}, 0, 0, 0);
        }
        // scale + rel-pos bias (bf16 window, fp32 math)
#pragma unroll
        for (int t = 0; t < 8; ++t) {
            int bb = (kt * 4 + (t >> 1)) * 63 + (t & 1) * 16 + m;
#pragma unroll
            for (int r = 0; r < 4; ++r)
                s8[t][r] = s8[t][r] * scale + bf2f(biasc[arow[r] - bb]);
        }
        // online softmax
        float alpha[4];
#pragma unroll
        for (int r = 0; r < 4; ++r) {
            float v = s8[0][r];
#pragma unroll
            for (int t = 1; t < 8; ++t) v = fmaxf(v, s8[t][r]);
            v = fmaxf(v, __shfl_xor(v, 1));
            v = fmaxf(v, __shfl_xor(v, 2));
            v = fmaxf(v, __shfl_xor(v, 4));
            v = fmaxf(v, __shfl_xor(v, 8));
            float mn = fmaxf(mrow[r], v);
            alpha[r] = __expf(mrow[r] - mn);
            mrow[r] = mn;
            float sum = 0.f;
#pragma unroll
            for (int t = 0; t < 8; ++t) {
                float p = __expf(s8[t][r] - mn);
                s8[t][r] = p;
                sum += p;
            }
            sum += __shfl_xor(sum, 1);
            sum += __shfl_xor(sum, 2);
            sum += __shfl_xor(sum, 4);
            sum += __shfl_xor(sum, 8);
            lrow[r] = lrow[r] * alpha[r] + sum;
        }
        // P (bf16) -> wave-local LDS stage (C-layout rows). No barrier needed:
        // Ps[wv] is read only by this wave; per-wave LDS ops are ordered by lgkmcnt.
#pragma unroll
        for (int t = 0; t < 8; ++t)
#pragma unroll
            for (int r = 0; r < 4; ++r)
                Ps[wv][q * 4 + r][t * 16 + m] = (u16)f2bf(s8[t][r]);
        // rescale O accumulator
#pragma unroll
        for (int dt = 0; dt < 2; ++dt)
#pragma unroll
            for (int r = 0; r < 4; ++r) acco[dt][r] *= alpha[r];
        // PV: A = P (A-layout from LDS), B = V (via Vt), 4 K-chunks x 2 d-tiles
#pragma unroll
        for (int c = 0; c < 4; ++c) {
            bf16x8 pf = *(const bf16x8*)&Ps[wv][m][c * 32 + q * 8];
#pragma unroll
            for (int dt = 0; dt < 2; ++dt) {
                bf16x8 vf = *(const bf16x8*)&Vt[dt * 16 + m][c * 32 + q * 8];
                acco[dt] = __builtin_amdgcn_mfma_f32_16x16x32_bf16(pf, vf, acco[dt], 0, 0, 0);
            }
        }
    }
    // epilogue: O = acco / l -> overwrite Q cols of this block's rows
#pragma unroll
    for (int r = 0; r < 4; ++r) {
        int l = qt * 64 + wv * 16 + q * 4 + r;
        float inv = 1.0f / lrow[r];
#pragma unroll
        for (int dt = 0; dt < 2; ++dt)
            qkvz[(size_t)l * 1536 + h * 32 + dt * 16 + m] = (u16)f2bf(acco[dt][r] * inv);
    }
}

extern "C" void kernel_launch(void* const* d_in, const int* in_sizes, int n_in,
                              void* d_out, int out_size, void* d_ws, size_t ws_size,
                              hipStream_t stream) {
    const float* x          = (const float*)d_in[0];
    const float* bias_table = (const float*)d_in[2];
    const float* qkv_w      = (const float*)d_in[3];
    const float* qkv_b      = (const float*)d_in[4];
    const float* proj_w     = (const float*)d_in[5];
    const float* proj_b     = (const float*)d_in[6];
    const float* n1g        = (const float*)d_in[7];
    const float* n1b        = (const float*)d_in[8];
    const float* n2g        = (const float*)d_in[9];
    const float* n2b        = (const float*)d_in[10];
    const float* fc1_w      = (const float*)d_in[11];
    const float* fc1_b      = (const float*)d_in[12];
    const float* fc2_w      = (const float*)d_in[13];
    const float* fc2_b      = (const float*)d_in[14];
    float* out = (float*)d_out;

    // ws (bf16 elems): wq_t @0 ; wp_t @786432 ; w1_t @1048576 ; w2_t @2097152 ;
    //   h[8192][512] @3145728 ; qkvbuf[4096][1536] @7340032 (hid reuses it)
    u16* ws16 = (u16*)d_ws;
    u16* wq_t = ws16;
    u16* wp_t = ws16 + 786432;
    u16* w1_t = ws16 + 1048576;
    u16* w2_t = ws16 + 2097152;
    u16* h    = ws16 + 3145728;
    u16* qkvb = ws16 + 7340032;
    u16* hid  = qkvb;

    wconv_kernel<<<dim3(48, 16), 256, 0, stream>>>(qkv_w, wq_t, 512, 1536);
    wconv_kernel<<<dim3(16, 16), 256, 0, stream>>>(proj_w, wp_t, 512, 512);
    wconv_kernel<<<dim3(64, 16), 256, 0, stream>>>(fc1_w, w1_t, 512, 2048);
    wconv_kernel<<<dim3(16, 64), 256, 0, stream>>>(fc2_w, w2_t, 2048, 512);

    ln_kernel<<<2048, 256, 0, stream>>>(x, n1g, n1b, h);

    for (int half = 0; half < 2; ++half) {
        size_t ro = (size_t)half * 4096;
        gemm_mfma<0, 0, 0, 128><<<dim3(768), 256, 0, stream>>>(
            h + ro * 512, 512, wq_t, qkv_b, nullptr, 0, qkvb, 1536, 512, 12);
        attn_mfma<<<dim3(1024), 256, 0, stream>>>(qkvb, bias_table);
        gemm_mfma<0, 1, 1, 64><<<dim3(512), 256, 0, stream>>>(
            qkvb, 1536, wp_t, proj_b, x + ro * 512, 512, out + ro * 512, 512, 512, 8);
    }

    ln_kernel<<<2048, 256, 0, stream>>>(out, n2g, n2b, h);

    for (int half = 0; half < 2; ++half) {
        size_t ro = (size_t)half * 4096;
        gemm_mfma<1, 0, 0, 128><<<dim3(1024), 256, 0, stream>>>(
            h + ro * 512, 512, w1_t, fc1_b, nullptr, 0, hid, 2048, 512, 16);
        gemm_mfma<0, 1, 1, 64><<<dim3(512), 256, 0, stream>>>(
            hid, 2048, w2_t, fc2_b, out + ro * 512, 512, out + ro * 512, 512, 2048, 8);
    }
}

// Round 14
// 350.626 us; speedup vs baseline: 1.1313x; 1.1313x over previous
//
#include <hip/hip_runtime.h>

typedef unsigned short u16;
typedef __attribute__((ext_vector_type(8))) short bf16x8;   // 8 bf16 in 4 VGPRs
typedef __attribute__((ext_vector_type(4))) float f32x4;

__device__ __forceinline__ float bf2f(unsigned int u) {
    union { unsigned int i; float f; } c; c.i = u << 16; return c.f;
}
__device__ __forceinline__ unsigned int f2bf(float f) {
    union { float f; unsigned int i; } c; c.f = f;
    unsigned int x = c.i;
    unsigned int r = x + 0x7FFFu + ((x >> 16) & 1u);
    return r >> 16;  // RNE; finite inputs
}

// async 16B global->LDS DMA. LDS dest = wave-uniform base + lane*16 (linear!).
__device__ __forceinline__ void gload_lds16(const u16* g, u16* l) {
    __builtin_amdgcn_global_load_lds(
        (__attribute__((address_space(1))) void*)const_cast<u16*>(g),
        (__attribute__((address_space(3))) void*)l,
        16, 0, 0);
}

// ---- weight convert+transpose: W fp32 [K][N] -> Wt bf16 [N][K], 32x32 LDS tiles ----
__global__ __launch_bounds__(256) void wconv_kernel(const float* __restrict__ W,
                                                    u16* __restrict__ Wt, int K, int N) {
    __shared__ u16 tile[32][36];
    int k0 = blockIdx.y * 32, n0 = blockIdx.x * 32;
    int t = threadIdx.x;
    int r = t >> 3, c4 = (t & 7) * 4;
    float4 v = *(const float4*)(W + (size_t)(k0 + r) * N + n0 + c4);
    tile[r][c4 + 0] = (u16)f2bf(v.x);
    tile[r][c4 + 1] = (u16)f2bf(v.y);
    tile[r][c4 + 2] = (u16)f2bf(v.z);
    tile[r][c4 + 3] = (u16)f2bf(v.w);
    __syncthreads();
    int n = t >> 3, k4 = (t & 7) * 4;
    u16 a0 = tile[k4 + 0][n], a1 = tile[k4 + 1][n];
    u16 a2 = tile[k4 + 2][n], a3 = tile[k4 + 3][n];
    uint2 st;
    st.x = (unsigned)a0 | ((unsigned)a1 << 16);
    st.y = (unsigned)a2 | ((unsigned)a3 << 16);
    *(uint2*)(Wt + (size_t)(n0 + n) * K + k0 + k4) = st;
}

// ---- LayerNorm fp32 in -> bf16 out. 256 threads = 4 waves, one row (512) per wave ----
__global__ __launch_bounds__(256) void ln_kernel(const float* __restrict__ x,
                                                 const float* __restrict__ g,
                                                 const float* __restrict__ b,
                                                 u16* __restrict__ y) {
    int row = blockIdx.x * 4 + (threadIdx.x >> 6);
    int t = threadIdx.x & 63;
    const float* xr = x + (size_t)row * 512 + t * 8;
    float4 a = *(const float4*)xr;
    float4 c = *(const float4*)(xr + 4);
    float v[8] = { a.x, a.y, a.z, a.w, c.x, c.y, c.z, c.w };
    float s = 0.f, ss = 0.f;
#pragma unroll
    for (int i = 0; i < 8; ++i) { s += v[i]; ss += v[i] * v[i]; }
#pragma unroll
    for (int off = 32; off; off >>= 1) {
        s  += __shfl_down(s, off);
        ss += __shfl_down(ss, off);
    }
    s = __shfl(s, 0); ss = __shfl(ss, 0);
    float mu = s * (1.0f / 512.0f);
    float var = ss * (1.0f / 512.0f) - mu * mu;
    float r = rsqrtf(var + 1e-5f);
    float4 g0 = *(const float4*)(g + t * 8);
    float4 g1 = *(const float4*)(g + t * 8 + 4);
    float4 b0 = *(const float4*)(b + t * 8);
    float4 b1 = *(const float4*)(b + t * 8 + 4);
    float gv[8] = { g0.x, g0.y, g0.z, g0.w, g1.x, g1.y, g1.z, g1.w };
    float bv[8] = { b0.x, b0.y, b0.z, b0.w, b1.x, b1.y, b1.z, b1.w };
    unsigned int o[4];
#pragma unroll
    for (int i = 0; i < 4; ++i) {
        float o0 = (v[2 * i] - mu) * r * gv[2 * i] + bv[2 * i];
        float o1 = (v[2 * i + 1] - mu) * r * gv[2 * i + 1] + bv[2 * i + 1];
        o[i] = f2bf(o0) | (f2bf(o1) << 16);
    }
    *(uint4*)(y + (size_t)row * 512 + t * 8) = make_uint4(o[0], o[1], o[2], o[3]);
}

// ---- MFMA GEMM: C[M,N] = act(A[M,K]bf16 @ Bt[N,K]bf16^T + bias fp32) (+res fp32) ----
// 64x64 tile (BN=64 for ALL GEMMs this round: round-12 measured BN 128->64 on the
// N=512 GEMMs as a clear win via 2x blocks/CU; qkv/fc1 now get the same mechanism:
// 3->6 and 4->8 blocks/CU). K-step 64 as TWO 32-planes, 2-phase double-buffered.
// 1D grid + XCD chunk-swizzle: wg = (bid&7)*(G/8) + bid>>3 (G%8==0).
template <int ACT, int RES, int COUT, int BN>
__global__ __launch_bounds__(256) void gemm_mfma(const u16* __restrict__ A, int lda,
                                                 const u16* __restrict__ Bt,
                                                 const float* __restrict__ bias,
                                                 const float* __restrict__ res, int ldres,
                                                 void* __restrict__ C, int ldC, int K,
                                                 int gx) {
    constexpr int JN = BN / 32;          // N-frags per wave (128->4, 64->2)
    __shared__ u16 As[2][2][64 * 32];    // [buf][plane][row][32] linear (gload_lds dest)
    __shared__ u16 Bs[2][2][BN * 32];
    int tid = threadIdx.x;
    int G = gridDim.x;
    int bid = blockIdx.x;
    int wg = (bid & 7) * (G >> 3) + (bid >> 3);   // XCD-contiguous chunks
    int bm = (wg / gx) * 64, bn = (wg % gx) * BN;
    int lane = tid & 63, wv = tid >> 6;
    int q = lane >> 4, lr = lane & 15;
    int wr = wv >> 1, wc = wv & 1;

    // staging (per 32-plane): A: wave wv rows [wv*16,+16), 1 instr (lane: row l>>2,
    // col (l&3)*8). B: wave wv rows [wv*(BN/4),+BN/4): 2 instrs if BN=128, 1 if 64.
    const u16* Ag = A + (size_t)(bm + wv * 16 + (lane >> 2)) * lda + (lane & 3) * 8;
    const u16* Bg = Bt + (size_t)(bn + wv * (BN / 4) + (lane >> 2)) * K + (lane & 3) * 8;
    int aoff  = (wv * 16) * 32;
    int boff0 = (wv * (BN / 4)) * 32;
    int boff1 = (wv * (BN / 4) + 16) * 32;   // BN==128 only
    int apf = (wr * 32 + lr) * 32 + q * 8;
    int bpf = (wc * (BN / 2) + lr) * 32 + q * 8;

    f32x4 acc[2][JN];
#pragma unroll
    for (int i = 0; i < 2; ++i)
#pragma unroll
        for (int j = 0; j < JN; ++j) acc[i][j] = (f32x4){0.f, 0.f, 0.f, 0.f};

    // prologue: stage k-tile 0 (both planes) into buf 0
#pragma unroll
    for (int p = 0; p < 2; ++p) {
        gload_lds16(Ag + p * 32, &As[0][p][aoff]);
        gload_lds16(Bg + p * 32, &Bs[0][p][boff0]);
        if constexpr (BN == 128)
            gload_lds16(Bg + (size_t)16 * K + p * 32, &Bs[0][p][boff1]);
    }
    __syncthreads();   // vmcnt(0) drain: tile 0 in LDS

    int cur = 0;
    for (int k0 = 0; k0 < K; k0 += 64) {
        int nxt = cur ^ 1;
        if (k0 + 64 < K) {   // issue next 64-K tile; overlaps both compute planes below
#pragma unroll
            for (int p = 0; p < 2; ++p) {
                gload_lds16(Ag + k0 + 64 + p * 32, &As[nxt][p][aoff]);
                gload_lds16(Bg + k0 + 64 + p * 32, &Bs[nxt][p][boff0]);
                if constexpr (BN == 128)
                    gload_lds16(Bg + (size_t)16 * K + k0 + 64 + p * 32, &Bs[nxt][p][boff1]);
            }
        }
#pragma unroll
        for (int p = 0; p < 2; ++p) {
            bf16x8 af[2], bfr[JN];
#pragma unroll
            for (int i = 0; i < 2; ++i) af[i] = *(const bf16x8*)&As[cur][p][apf + i * 16 * 32];
#pragma unroll
            for (int j = 0; j < JN; ++j) bfr[j] = *(const bf16x8*)&Bs[cur][p][bpf + j * 16 * 32];
#pragma unroll
            for (int i = 0; i < 2; ++i)
#pragma unroll
                for (int j = 0; j < JN; ++j)
                    acc[i][j] = __builtin_amdgcn_mfma_f32_16x16x32_bf16(af[i], bfr[j], acc[i][j], 0, 0, 0);
        }
        __syncthreads();   // drains prefetch vmcnt + all waves done with buf[cur]
        cur = nxt;
    }

    float bv[JN];
#pragma unroll
    for (int j = 0; j < JN; ++j)
        bv[j] = bias ? bias[bn + wc * (BN / 2) + j * 16 + lr] : 0.f;
#pragma unroll
    for (int i = 0; i < 2; ++i) {
#pragma unroll
        for (int j = 0; j < JN; ++j) {
            int col = bn + wc * (BN / 2) + j * 16 + lr;
#pragma unroll
            for (int r = 0; r < 4; ++r) {
                int row = bm + wr * 32 + i * 16 + q * 4 + r;
                float v = acc[i][j][r] + bv[j];
                if (ACT) v = 0.5f * v * (1.0f + erff(v * 0.7071067811865475f));
                if (RES) v += res[(size_t)row * ldres + col];
                if (COUT == 0) ((u16*)C)[(size_t)row * ldC + col] = (u16)f2bf(v);
                else           ((float*)C)[(size_t)row * ldC + col] = v;
            }
        }
    }
}

// ---- Flash attention (MFMA): 1D grid 1024, XCD-grouped decode (K/V + bias column
// fetched once per XCD). qkv: [4096][1536] bf16; Q [0,512), K [512,1024), V [1024,1536).
// ROUND-12 MEASURED-BEST VARIANT (55.4 us) — byte-for-byte revert of the round-13
// bf16-bias experiment (+36% regression: occupancy rose but per-wave pipeline was
// damaged — VGPR 68->56, HBM BW 207->152 GB/s; occupancy was NOT binding).
// fp32 windowed biasc [qt*126, qt*126+2112); __expf + shfl-sum softmax;
// row-contiguous K/V staging with register prefetch.
__global__ __launch_bounds__(256) void attn_mfma(u16* __restrict__ qkv,
                                                 const float* __restrict__ bias_table) {
    __shared__ u16 Ks[128][40];        // [key][d]  stride 80B (16B-aligned)
    __shared__ u16 Vt[32][136];        // [d][key]  stride 272B
    __shared__ u16 Ps[4][16][136];     // per-wave P stage [row][key]
    __shared__ float biasc[2112];      // bias window [qt*126, qt*126+2112)
    int tid = threadIdx.x;
    int bid = blockIdx.x;
    // decode: xcd = bid&7, i = bid>>3; group = xcd*8 + (i>>4) in [0,64); qt = i&15
    int grp = (bid & 7) * 8 + ((bid >> 3) >> 4);
    int qt = (bid >> 3) & 15;
    int h = grp & 15, z = grp >> 4;
    u16* qkvz = qkv + (size_t)z * 1024 * 1536;

    int bbase = qt * 126;
    for (int i = tid; i < 2112; i += 256) {
        int gi = bbase + i;
        if (gi < 3969) biasc[i] = bias_table[(size_t)gi * 16 + h];
    }

    int lane = tid & 63, wv = tid >> 6;
    int q = lane >> 4, m = lane & 15;

    // Q A-fragment (held for the whole block): rows qt*64 + wv*16 + m
    int qrow = qt * 64 + wv * 16 + m;
    bf16x8 qf = *(const bf16x8*)(qkvz + (size_t)qrow * 1536 + h * 32 + q * 8);

    // local bias base: idx_local = arow[r] - bb, arow = (inner>>5)*63 + (inner&31) + 1984
    int arow[4];
#pragma unroll
    for (int r = 0; r < 4; ++r) {
        int inner = wv * 16 + q * 4 + r;
        arow[r] = (inner >> 5) * 63 + (inner & 31) + 1984;
    }

    const float scale = 0.17677669529663687f;  // 1/sqrt(32)
    float mrow[4] = { -1e30f, -1e30f, -1e30f, -1e30f };
    float lrow[4] = { 0.f, 0.f, 0.f, 0.f };
    f32x4 acco[2] = { (f32x4){0.f,0.f,0.f,0.f}, (f32x4){0.f,0.f,0.f,0.f} };

    // K/V staging assignment + software-pipelined prefetch (issue-early / write-late)
    int key = tid >> 1, dh = (tid & 1) * 16;
    const u16* kvsrc = qkvz + (size_t)key * 1536 + 512 + h * 32 + dh;  // K of key row
    uint4 pk0, pk1, pv0, pv1;
    pk0 = *(const uint4*)(kvsrc);
    pk1 = *(const uint4*)(kvsrc + 8);
    pv0 = *(const uint4*)(kvsrc + 512);     // V is +512 cols from K
    pv1 = *(const uint4*)(kvsrc + 520);

    for (int kt = 0; kt < 8; ++kt) {
        __syncthreads();   // all waves done reading Ks/Vt of tile kt-1 (covers biasc at kt=0)
        *(uint4*)&Ks[key][dh] = pk0;
        *(uint4*)&Ks[key][dh + 8] = pk1;
        {
            u16 tmp[16];
            *(uint4*)tmp = pv0; *(uint4*)(tmp + 8) = pv1;
#pragma unroll
            for (int j = 0; j < 16; ++j) Vt[dh + j][key] = tmp[j];
        }
        __syncthreads();
        if (kt < 7) {   // issue next tile's loads now; latency hides under compute below
            const u16* src = kvsrc + (size_t)(kt + 1) * 128 * 1536;
            pk0 = *(const uint4*)(src);
            pk1 = *(const uint4*)(src + 8);
            pv0 = *(const uint4*)(src + 512);
            pv1 = *(const uint4*)(src + 520);
        }

        // QK: 8 sub-tiles of 16 keys, full hd=32 in one MFMA each
        f32x4 s8[8];
#pragma unroll
        for (int t = 0; t < 8; ++t) {
            bf16x8 kf = *(const bf16x8*)&Ks[t * 16 + m][q * 8];
            s8[t] = __builtin_amdgcn_mfma_f32_16x16x32_bf16(
                qf, kf, (f32x4){0.f,0.f,0.f,0.f}, 0, 0, 0);
        }
        // scale + rel-pos bias, windowed LDS lookup
#pragma unroll
        for (int t = 0; t < 8; ++t) {
            int bb = (kt * 4 + (t >> 1)) * 63 + (t & 1) * 16 + m;
#pragma unroll
            for (int r = 0; r < 4; ++r)
                s8[t][r] = s8[t][r] * scale + biasc[arow[r] - bb];
        }
        // online softmax
        float alpha[4];
#pragma unroll
        for (int r = 0; r < 4; ++r) {
            float v = s8[0][r];
#pragma unroll
            for (int t = 1; t < 8; ++t) v = fmaxf(v, s8[t][r]);
            v = fmaxf(v, __shfl_xor(v, 1));
            v = fmaxf(v, __shfl_xor(v, 2));
            v = fmaxf(v, __shfl_xor(v, 4));
            v = fmaxf(v, __shfl_xor(v, 8));
            float mn = fmaxf(mrow[r], v);
            alpha[r] = __expf(mrow[r] - mn);
            mrow[r] = mn;
            float sum = 0.f;
#pragma unroll
            for (int t = 0; t < 8; ++t) {
                float p = __expf(s8[t][r] - mn);
                s8[t][r] = p;
                sum += p;
            }
            sum += __shfl_xor(sum, 1);
            sum += __shfl_xor(sum, 2);
            sum += __shfl_xor(sum, 4);
            sum += __shfl_xor(sum, 8);
            lrow[r] = lrow[r] * alpha[r] + sum;
        }
        // P (bf16) -> wave-local LDS stage (C-layout rows). No barrier needed:
        // Ps[wv] is read only by this wave; per-wave LDS ops are ordered by lgkmcnt.
#pragma unroll
        for (int t = 0; t < 8; ++t)
#pragma unroll
            for (int r = 0; r < 4; ++r)
                Ps[wv][q * 4 + r][t * 16 + m] = (u16)f2bf(s8[t][r]);
        // rescale O accumulator
#pragma unroll
        for (int dt = 0; dt < 2; ++dt)
#pragma unroll
            for (int r = 0; r < 4; ++r) acco[dt][r] *= alpha[r];
        // PV: A = P (A-layout from LDS), B = V (via Vt), 4 K-chunks x 2 d-tiles
#pragma unroll
        for (int c = 0; c < 4; ++c) {
            bf16x8 pf = *(const bf16x8*)&Ps[wv][m][c * 32 + q * 8];
#pragma unroll
            for (int dt = 0; dt < 2; ++dt) {
                bf16x8 vf = *(const bf16x8*)&Vt[dt * 16 + m][c * 32 + q * 8];
                acco[dt] = __builtin_amdgcn_mfma_f32_16x16x32_bf16(pf, vf, acco[dt], 0, 0, 0);
            }
        }
    }
    // epilogue: O = acco / l -> overwrite Q cols of this block's rows
#pragma unroll
    for (int r = 0; r < 4; ++r) {
        int l = qt * 64 + wv * 16 + q * 4 + r;
        float inv = 1.0f / lrow[r];
#pragma unroll
        for (int dt = 0; dt < 2; ++dt)
            qkvz[(size_t)l * 1536 + h * 32 + dt * 16 + m] = (u16)f2bf(acco[dt][r] * inv);
    }
}

extern "C" void kernel_launch(void* const* d_in, const int* in_sizes, int n_in,
                              void* d_out, int out_size, void* d_ws, size_t ws_size,
                              hipStream_t stream) {
    const float* x          = (const float*)d_in[0];
    const float* bias_table = (const float*)d_in[2];
    const float* qkv_w      = (const float*)d_in[3];
    const float* qkv_b      = (const float*)d_in[4];
    const float* proj_w     = (const float*)d_in[5];
    const float* proj_b     = (const float*)d_in[6];
    const float* n1g        = (const float*)d_in[7];
    const float* n1b        = (const float*)d_in[8];
    const float* n2g        = (const float*)d_in[9];
    const float* n2b        = (const float*)d_in[10];
    const float* fc1_w      = (const float*)d_in[11];
    const float* fc1_b      = (const float*)d_in[12];
    const float* fc2_w      = (const float*)d_in[13];
    const float* fc2_b      = (const float*)d_in[14];
    float* out = (float*)d_out;

    // ws (bf16 elems): wq_t @0 ; wp_t @786432 ; w1_t @1048576 ; w2_t @2097152 ;
    //   h[8192][512] @3145728 ; qkvbuf[4096][1536] @7340032 (hid reuses it)
    u16* ws16 = (u16*)d_ws;
    u16* wq_t = ws16;
    u16* wp_t = ws16 + 786432;
    u16* w1_t = ws16 + 1048576;
    u16* w2_t = ws16 + 2097152;
    u16* h    = ws16 + 3145728;
    u16* qkvb = ws16 + 7340032;
    u16* hid  = qkvb;

    wconv_kernel<<<dim3(48, 16), 256, 0, stream>>>(qkv_w, wq_t, 512, 1536);
    wconv_kernel<<<dim3(16, 16), 256, 0, stream>>>(proj_w, wp_t, 512, 512);
    wconv_kernel<<<dim3(64, 16), 256, 0, stream>>>(fc1_w, w1_t, 512, 2048);
    wconv_kernel<<<dim3(16, 64), 256, 0, stream>>>(fc2_w, w2_t, 2048, 512);

    ln_kernel<<<2048, 256, 0, stream>>>(x, n1g, n1b, h);

    for (int half = 0; half < 2; ++half) {
        size_t ro = (size_t)half * 4096;
        gemm_mfma<0, 0, 0, 64><<<dim3(1536), 256, 0, stream>>>(
            h + ro * 512, 512, wq_t, qkv_b, nullptr, 0, qkvb, 1536, 512, 24);
        attn_mfma<<<dim3(1024), 256, 0, stream>>>(qkvb, bias_table);
        gemm_mfma<0, 1, 1, 64><<<dim3(512), 256, 0, stream>>>(
            qkvb, 1536, wp_t, proj_b, x + ro * 512, 512, out + ro * 512, 512, 512, 8);
    }

    ln_kernel<<<2048, 256, 0, stream>>>(out, n2g, n2b, h);

    for (int half = 0; half < 2; ++half) {
        size_t ro = (size_t)half * 4096;
        gemm_mfma<1, 0, 0, 64><<<dim3(2048), 256, 0, stream>>>(
            h + ro * 512, 512, w1_t, fc1_b, nullptr, 0, hid, 2048, 512, 32);
        gemm_mfma<0, 1, 1, 64><<<dim3(512), 256, 0, stream>>>(
            hid, 2048, w2_t, fc2_b, out + ro * 512, 512, out + ro * 512, 512, 2048, 8);
    }
}